// Round 2
// 362.121 us; speedup vs baseline: 1.0802x; 1.0802x over previous
//
#include <hip/hip_runtime.h>
#include <hip/hip_bf16.h>

#define B_  2048
#define L_  200
#define D_  128
#define H0_ 80
#define H1_ 40
#define BPB 4              // batches per block
#define NTILE 13           // 16-row score tiles per batch (208 rows, 8 pad)
#define TT_ (BPB*NTILE)    // 52 tiles per block, 13 per wave (even)

// ws layout (shorts): Bg[80][256] @0 | w1t[48][96] @20480 | w0p[128][84] @25088
#define WS_BG  0
#define WS_W1T 20480
#define WS_W0P 25088
#define WS_TOT 35840

typedef __attribute__((ext_vector_type(8))) short short8;
typedef __attribute__((ext_vector_type(4))) float floatx4;

__device__ __forceinline__ short f2bf(float f) {
    unsigned u = __float_as_uint(f);
    u += 0x7fffu + ((u >> 16) & 1u);   // round-to-nearest-even
    return (short)(u >> 16);
}
__device__ __forceinline__ float bf2f(short s) {
    return __uint_as_float(((unsigned)(unsigned short)s) << 16);
}

// ---------------- prep: pure weight transform, one pass ---------------------
// feat@W0 = hist@(W0a+W0c) + (hist.*tgt)@W0d + [tgt@(W0b-W0c)+b0]
__global__ __launch_bounds__(256) void prep_kernel(
    const float* __restrict__ W0, const float* __restrict__ W1,
    short* __restrict__ ws)
{
    for (int i = blockIdx.x * 256 + threadIdx.x; i < WS_TOT; i += 64 * 256) {
        short v;
        if (i < WS_W1T) {                       // Bg[h][k]: k<128 W0a+W0c, k>=128 W0d
            int h = i >> 8, k = i & 255;
            float x = (k < 128) ? (W0[(size_t)k * H0_ + h] + W0[(size_t)(256 + k) * H0_ + h])
                                : W0[(size_t)(384 + (k - 128)) * H0_ + h];
            v = f2bf(x);
        } else if (i < WS_W0P) {                // w1t[n][k] 48x96, zero-padded
            int j = i - WS_W1T;
            int n = j / 96, k = j - n * 96;
            v = (n < H1_ && k < H0_) ? f2bf(W1[(size_t)k * H1_ + n]) : (short)0;
        } else {                                // w0p[d][h] 128x84 = bf16(W0b-W0c), padded
            int j = i - WS_W0P;
            int d = j / 84, h = j - d * 84;
            v = (h < H0_) ? f2bf(W0[(size_t)(128 + d) * H0_ + h] - W0[(size_t)(256 + d) * H0_ + h])
                          : (short)0;
        }
        ws[i] = v;
    }
}

// ---------------- fused: scores + softmax + weighted sum, 1 HBM pass --------
__global__ __launch_bounds__(256, 2) void fused_kernel(
    const float* __restrict__ hist, const float* __restrict__ tgt,
    const int* __restrict__ mask, const short* __restrict__ ws,
    const float* __restrict__ b0p, const float* __restrict__ b1,
    const float* __restrict__ W2, const float* __restrict__ b2,
    float* __restrict__ out)
{
    __shared__ __align__(16) short Bs[H0_][264];       // 42240 B; prologue aliases w0p stage
    __shared__ __align__(16) short h0t[4][16][104];    // 13312 B, wave-private
    __shared__ float tgs4[BPB][D_];                    // 2048 B
    __shared__ float beffs[BPB][H0_];                  // 1280 B
    __shared__ float scores4[BPB][208];                // 3328 B; prologue aliases red3
    __shared__ float red[8];
    __shared__ float p0[D_], p1[D_];                   // 1024 B
    // total ~63.3 KB -> 2 blocks/CU

    const int tid = threadIdx.x;
    const int wave = tid >> 6, lane = tid & 63;
    const int col = lane & 15, quad = lane >> 4;
    const int bbase = blockIdx.x * BPB;

    short* w0s = &Bs[0][0];            // [128][84] bf16(W0b-W0c), freed before Bs staged
    float* red3 = &scores4[0][0];      // [3][80] partials, freed before scores written

    // ---- prologue: stage w0p + 4 tgt rows ----
    for (int i = tid; i < 1344; i += 256)
        *(short8*)(w0s + i * 8) = *(const short8*)(ws + WS_W0P + i * 8);
    for (int i = tid; i < BPB * D_; i += 256)
        tgs4[i >> 7][i & 127] = tgt[(size_t)(bbase + (i >> 7)) * D_ + (i & 127)];
    __syncthreads();

    // ---- beff for 4 batches: beff[h] = b0[h] + tgt . (W0b-W0c)[:,h] ----
    for (int bb = 0; bb < BPB; ++bb) {
        if (tid < 240) {
            int seg = tid / 80, h = tid - seg * 80;
            int d0 = seg * 43, d1 = (seg == 2) ? D_ : d0 + 43;
            float s = 0.f;
            #pragma unroll 8
            for (int d = d0; d < d1; ++d) s += tgs4[bb][d] * bf2f(w0s[d * 84 + h]);
            red3[seg * H0_ + h] = s;
        }
        __syncthreads();
        if (tid < H0_)
            beffs[bb][tid] = b0p[tid] + red3[tid] + red3[H0_ + tid] + red3[2 * H0_ + tid];
        __syncthreads();
    }

    // ---- stage Bs (overwrites w0s region), zero h0t tail, hoist w1 frags ----
    for (int i = tid; i < 2560; i += 256) {
        int h = i >> 5, k0 = (i & 31) * 8;
        *(short8*)&Bs[h][k0] = *(const short8*)(ws + WS_BG + (h << 8) + k0);
    }
    if (tid < 192) {
        int w = tid / 48, rem = tid % 48, row = rem / 3, c = 80 + (rem % 3) * 8;
        *(short8*)&h0t[w][row][c] = (short8)0;
    }
    short8 w1f[3][3];
    #pragma unroll
    for (int ks = 0; ks < 3; ++ks)
        #pragma unroll
        for (int nt = 0; nt < 3; ++nt)
            w1f[ks][nt] = *(const short8*)(ws + WS_W1T + (nt * 16 + col) * 96 + ks * 32 + quad * 8);
    float b1r[3], w2r[3];
    #pragma unroll
    for (int nt = 0; nt < 3; ++nt) {
        int h = nt * 16 + col;
        b1r[nt] = (h < H1_) ? b1[h] : 0.f;
        w2r[nt] = (h < H1_) ? W2[h] : 0.f;
    }
    const float b2v = b2[0];
    __syncthreads();

    // ---- score phase: 52 tiles, 13 per wave ----
    for (int tt = wave; tt < TT_; tt += 4) {
        const int bb = tt / NTILE, t = tt - bb * NTILE;
        const int l = t * 16 + col;
        const int lc = (l < L_) ? l : (L_ - 1);       // clamp pad rows (garbage, masked later)
        const float* ap = hist + ((size_t)(bbase + bb) * L_ + lc) * D_ + quad * 8;

        floatx4 A[8], T8[8];
        #pragma unroll
        for (int u = 0; u < 8; ++u) A[u] = *(const floatx4*)(ap + (u >> 1) * 32 + (u & 1) * 4);
        #pragma unroll
        for (int u = 0; u < 8; ++u)
            T8[u] = *(const floatx4*)&tgs4[bb][quad * 8 + (u >> 1) * 32 + (u & 1) * 4];

        short8 ah[4], ag[4];
        #pragma unroll
        for (int ks = 0; ks < 4; ++ks) {
            short8 h8, g8;
            #pragma unroll
            for (int j = 0; j < 8; ++j) {
                float hv = A[2 * ks + (j >> 2)][j & 3];
                float tv = T8[2 * ks + (j >> 2)][j & 3];
                h8[j] = f2bf(hv);
                g8[j] = f2bf(hv * tv);
            }
            ah[ks] = h8; ag[ks] = g8;
        }

        // layer 0: K=256 (128 hist + 128 prod)
        floatx4 c0[5];
        #pragma unroll
        for (int nt = 0; nt < 5; ++nt) c0[nt] = (floatx4)0.f;
        #pragma unroll
        for (int ks = 0; ks < 4; ++ks)
            #pragma unroll
            for (int nt = 0; nt < 5; ++nt) {
                short8 bfr = *(const short8*)&Bs[nt * 16 + col][ks * 32 + quad * 8];
                c0[nt] = __builtin_amdgcn_mfma_f32_16x16x32_bf16(ah[ks], bfr, c0[nt], 0, 0, 0);
            }
        #pragma unroll
        for (int ks = 0; ks < 4; ++ks)
            #pragma unroll
            for (int nt = 0; nt < 5; ++nt) {
                short8 bfr = *(const short8*)&Bs[nt * 16 + col][128 + ks * 32 + quad * 8];
                c0[nt] = __builtin_amdgcn_mfma_f32_16x16x32_bf16(ag[ks], bfr, c0[nt], 0, 0, 0);
            }

        // bias+relu -> wave-private h0 tile (bias uniform per column now)
        #pragma unroll
        for (int nt = 0; nt < 5; ++nt) {
            float be = beffs[bb][nt * 16 + col];
            #pragma unroll
            for (int r = 0; r < 4; ++r) {
                float v = c0[nt][r] + be;
                v = v > 0.f ? v : 0.f;
                h0t[wave][quad * 4 + r][nt * 16 + col] = f2bf(v);
            }
        }

        // layer 1
        floatx4 c1[3];
        #pragma unroll
        for (int nt = 0; nt < 3; ++nt) c1[nt] = (floatx4)0.f;
        #pragma unroll
        for (int ks = 0; ks < 3; ++ks) {
            short8 a1 = *(const short8*)&h0t[wave][col][ks * 32 + quad * 8];
            #pragma unroll
            for (int nt = 0; nt < 3; ++nt)
                c1[nt] = __builtin_amdgcn_mfma_f32_16x16x32_bf16(a1, w1f[ks][nt], c1[nt], 0, 0, 0);
        }

        // layer 2 + 16-lane reduce -> LDS scores
        float s4[4] = {0.f, 0.f, 0.f, 0.f};
        #pragma unroll
        for (int nt = 0; nt < 3; ++nt)
            #pragma unroll
            for (int r = 0; r < 4; ++r) {
                float v = c1[nt][r] + b1r[nt];
                v = v > 0.f ? v : 0.f;
                s4[r] += v * w2r[nt];
            }
        #pragma unroll
        for (int r = 0; r < 4; ++r) {
            s4[r] += __shfl_xor(s4[r], 1, 16);
            s4[r] += __shfl_xor(s4[r], 2, 16);
            s4[r] += __shfl_xor(s4[r], 4, 16);
            s4[r] += __shfl_xor(s4[r], 8, 16);
        }
        if (col == 0) {
            #pragma unroll
            for (int r = 0; r < 4; ++r)
                scores4[bb][t * 16 + quad * 4 + r] = s4[r] + b2v;
        }
    }
    __syncthreads();

    // ---- per-batch softmax + weighted sum (hist re-read is L2/L3-hot) ----
    for (int bb = 0; bb < BPB; ++bb) {
        const int b = bbase + bb;

        float sc = -3.0e38f;
        if (tid < L_) {
            sc = scores4[bb][tid];
            if (mask[(size_t)b * L_ + tid] == 0) sc -= 1e9f;
        }
        float m = sc;
        #pragma unroll
        for (int off = 32; off >= 1; off >>= 1) m = fmaxf(m, __shfl_xor(m, off, 64));
        if (lane == 0) red[wave] = m;
        __syncthreads();
        m = fmaxf(fmaxf(red[0], red[1]), fmaxf(red[2], red[3]));
        float e = (tid < L_) ? __expf(sc - m) : 0.f;
        float s = e;
        #pragma unroll
        for (int off = 32; off >= 1; off >>= 1) s += __shfl_xor(s, off, 64);
        if (lane == 0) red[4 + wave] = s;
        __syncthreads();
        s = red[4] + red[5] + red[6] + red[7];
        float av = e * (1.0f / s);
        if (tid < L_) {
            scores4[bb][tid] = av;                                   // reuse as attn weights
            out[(size_t)B_ * D_ + (size_t)b * L_ + tid] = av;
        }
        __syncthreads();

        const int half = tid >> 7, d = tid & 127;
        const float* hb = hist + ((size_t)b * L_ + half * 100) * D_ + d;
        float acc = 0.f;
        #pragma unroll 25
        for (int l = 0; l < 100; ++l)
            acc = fmaf(scores4[bb][half * 100 + l], hb[(size_t)l * D_], acc);
        if (half) p1[d] = acc; else p0[d] = acc;
        __syncthreads();
        if (tid < D_) out[(size_t)b * D_ + tid] = p0[tid] + p1[tid];
    }
}

extern "C" void kernel_launch(void* const* d_in, const int* in_sizes, int n_in,
                              void* d_out, int out_size, void* d_ws, size_t ws_size,
                              hipStream_t stream) {
    const float* hist = (const float*)d_in[0];
    const float* tgt  = (const float*)d_in[1];
    const int*   mask = (const int*)d_in[2];
    const float* W0   = (const float*)d_in[3];
    const float* b0   = (const float*)d_in[4];
    const float* W1   = (const float*)d_in[5];
    const float* b1   = (const float*)d_in[6];
    const float* W2   = (const float*)d_in[7];
    const float* b2   = (const float*)d_in[8];

    short* ws = (short*)d_ws;

    prep_kernel<<<64, 256, 0, stream>>>(W0, W1, ws);
    fused_kernel<<<B_ / BPB, 256, 0, stream>>>(hist, tgt, mask, ws, b0, b1, W2, b2,
                                               (float*)d_out);
}